// Round 5
// baseline (162.882 us; speedup 1.0000x reference)
//
#include <hip/hip_runtime.h>
#include <hip/hip_bf16.h>

namespace {
constexpr int kB   = 1000;
constexpr int kT   = 20000;
constexpr int kKt  = 181;
constexpr int kInW = kT + kKt - 1;   // 20180
constexpr int TW     = 128;          // output cols per wave-job (8 tiles of 16)
constexpr int NTILE  = TW / 16;      // 8
constexpr int NFRAG  = NTILE + 12;   // 20 sliding-window fragment slots
constexpr int NB     = (kB + 15) / 16;        // 63 row groups
constexpr int NS     = (kT + TW - 1) / TW;    // 157 col strips
constexpr int NJOBS  = NB * NS;               // 9891 wave-jobs
constexpr int WPB    = 4;                     // waves per block
constexpr int NBLK   = (NJOBS + WPB - 1) / WPB;

typedef short bf16x8 __attribute__((ext_vector_type(8)));
typedef float f32x4  __attribute__((ext_vector_type(4)));

__device__ __forceinline__ unsigned pack_bf16x2(float lo, float hi) {
  __hip_bfloat162 h = __float22bfloat162_rn(float2{lo, hi});
  unsigned w;
  __builtin_memcpy(&w, &h, 4);
  return w;
}

template <bool B> struct TailTag { static constexpr bool value = B; };
} // namespace

__global__ __launch_bounds__(256, 3)
void biexp_stream(const float* __restrict__ u, const float* __restrict__ kern,
                  float* __restrict__ out) {
  __shared__ float lds_k[kKt];
  const int tid = threadIdx.x;
  if (tid < kKt) lds_k[tid] = kern[tid];
  __syncthreads();   // only barrier in the kernel (taps); before any early return

  const int lane = tid & 63;
  const int wave = tid >> 6;
  const int quad = lane >> 4;
  const int nn   = lane & 15;

  // ---- Toeplitz B fragments: B[k][n] = w(k-n), w(i)=kern[180-i]; lane-only, job-independent
  union { bf16x8 v; unsigned w[4]; } bfr[7];
  #pragma unroll
  for (int c = 0; c < 7; ++c) {
    #pragma unroll
    for (int jj = 0; jj < 4; ++jj) {
      int i0 = 32 * c + quad * 8 + 2 * jj - nn;  // k - n for element 2*jj
      float f0 = (i0 >= 0     && i0 < kKt)     ? lds_k[kKt - 1 - i0] : 0.0f;
      float f1 = (i0 + 1 >= 0 && i0 + 1 < kKt) ? lds_k[kKt - 2 - i0] : 0.0f;
      bfr[c].w[jj] = pack_bf16x2(f0, f1);
    }
  }

  const int job = blockIdx.x * WPB + wave;
  if (job >= NJOBS) return;
  const int jb = job / NS;        // row group   (const divisor -> magic mul)
  const int js = job - jb * NS;   // col strip
  const int b0 = jb * 16;
  const int t0 = js * TW;

  const int row = min(b0 + nn, kB - 1);
  const float* __restrict__ urow = u + (size_t)row * kInW;

  // Fragment at k-offset 16*m: lane holds u[row][t0+16m+quad*8 .. +7] as bf16x8.
  // TAIL (last strip only): per-ELEMENT clamp — cols >= kInW have zero Toeplitz
  // weight for every unmasked output, so a duplicated u[kInW-1] there is harmless;
  // cols < kInW must stay exact (round-3 bug: group-level clamp shifted valid
  // elements 20176..20179, corrupting outputs t=19996..19999).
  auto body = [&](auto tail_tag) {
    constexpr bool TAIL = decltype(tail_tag)::value;
    auto load_frag = [&](int m) -> bf16x8 {
      int col = t0 + 16 * m + quad * 8;
      union { bf16x8 v; unsigned w[4]; } r;
      if (!TAIL || col + 8 <= kInW) {
        f32x4 a = *(const f32x4*)(urow + col);
        f32x4 b = *(const f32x4*)(urow + col + 4);
        r.w[0] = pack_bf16x2(a[0], a[1]);
        r.w[1] = pack_bf16x2(a[2], a[3]);
        r.w[2] = pack_bf16x2(b[0], b[1]);
        r.w[3] = pack_bf16x2(b[2], b[3]);
      } else {
        float e[8];
        #pragma unroll
        for (int j = 0; j < 8; ++j) e[j] = urow[min(col + j, kInW - 1)];
        r.w[0] = pack_bf16x2(e[0], e[1]);
        r.w[1] = pack_bf16x2(e[2], e[3]);
        r.w[2] = pack_bf16x2(e[4], e[5]);
        r.w[3] = pack_bf16x2(e[6], e[7]);
      }
      return r.v;
    };

    bf16x8 F[NFRAG];
    #pragma unroll
    for (int m = 0; m < 14; ++m) F[m] = load_frag(m);   // window for tiles 0 and 1

    #pragma unroll
    for (int jt = 0; jt < NTILE; ++jt) {
      if (jt + 14 < NFRAG) F[jt + 14] = load_frag(jt + 14);  // 2-tile lookahead
      // tile jt, chunk c uses fragment m = jt + 2c; split acc to shorten dep chain
      f32x4 acc0 = {0.f, 0.f, 0.f, 0.f};
      f32x4 acc1 = {0.f, 0.f, 0.f, 0.f};
      #pragma unroll
      for (int c = 0; c < 7; c += 2)
        acc0 = __builtin_amdgcn_mfma_f32_16x16x32_bf16(F[jt + 2 * c], bfr[c].v, acc0, 0, 0, 0);
      #pragma unroll
      for (int c = 1; c < 7; c += 2)
        acc1 = __builtin_amdgcn_mfma_f32_16x16x32_bf16(F[jt + 2 * c], bfr[c].v, acc1, 0, 0, 0);
      const int gt = t0 + 16 * jt + nn;
      if (gt < kT) {                     // uniform per 16-col tile (kT % 16 == 0)
        #pragma unroll
        for (int r = 0; r < 4; ++r) {
          const int gb = b0 + quad * 4 + r;
          if (gb < kB) out[(size_t)gb * kT + gt] = acc0[r] + acc1[r];
        }
      }
    }
  };

  if (js == NS - 1) body(TailTag<true>{});
  else              body(TailTag<false>{});
}

extern "C" void kernel_launch(void* const* d_in, const int* in_sizes, int n_in,
                              void* d_out, int out_size, void* d_ws, size_t ws_size,
                              hipStream_t stream) {
  const float* u  = (const float*)d_in[0];
  const float* kn = (const float*)d_in[1];
  float* out = (float*)d_out;
  hipLaunchKernelGGL(biexp_stream, dim3(NBLK, 1, 1), dim3(256, 1, 1), 0, stream,
                     u, kn, out);
}